// Round 12
// baseline (218.789 us; speedup 1.0000x reference)
//
#include <hip/hip_runtime.h>

#define N_NODES 100000
#define N_EDGES 1600000
#define IN_DIM  128
#define HIDDEN  128
#define OUT_DIM 64

#define BUCK_SHIFT 6                          // 64-node buckets
#define BUCK_SZ    64
#define NB_BUCK ((N_NODES + BUCK_SZ - 1) / BUCK_SZ)   // 1563 buckets
#define EPB 4096                              // edges per partition block (R1-proven)
#define NBLK_E ((N_EDGES + EPB - 1) / EPB)    // 391 partition blocks
#define GB1 ((N_NODES + 127) / 128)           // 782 GEMM1 blocks
#define CAP 1536                              // bucket capacity (mean 1024 + 16 sigma)
#define PCAP 1984                             // padded capacity, mult of 8

typedef __attribute__((ext_vector_type(8))) short bf8_t;   // 8 x bf16 (4 VGPRs)
typedef __attribute__((ext_vector_type(4))) float f4_t;    // MFMA accumulator

__device__ __forceinline__ ushort f2b(float f) {           // fp32 -> bf16 RNE
    unsigned int u = __float_as_uint(f);
    u += 0x7fffu + ((u >> 16) & 1u);
    return (ushort)(u >> 16);
}
__device__ __forceinline__ float b2f_lo(unsigned int u) { return __uint_as_float(u << 16); }
__device__ __forceinline__ float b2f_hi(unsigned int u) { return __uint_as_float(u & 0xffff0000u); }

// ---- k_prep: w1b + w2b conversion, cursor zero, sentinels ----
__global__ __launch_bounds__(256) void k_prep(const float* __restrict__ W1,
                                              const float* __restrict__ W2,
                                              ushort* __restrict__ w1b,
                                              ushort* __restrict__ w2b,
                                              int* __restrict__ cursor,
                                              float* __restrict__ dinv,
                                              ushort* __restrict__ h) {
    int b = blockIdx.x, t = threadIdx.x;
    if (b < 8) {                               // W1 -> bf16 n-major (16384 elems)
        int start = b * 2048;
        #pragma unroll
        for (int j = 0; j < 8; j++) {
            int i = start + j * 256 + t;       // i = n*128 + k
            int n = i >> 7, k = i & 127;
            w1b[i] = f2b(W1[k * 128 + n]);
        }
    } else if (b < 12) {                       // W2 -> bf16 n-major (8192 elems)
        int start = (b - 8) * 2048;
        #pragma unroll
        for (int j = 0; j < 8; j++) {
            int i = start + j * 256 + t;       // i = n*128 + k
            int n = i >> 7, k = i & 127;
            w2b[i] = f2b(W2[k * 64 + n]);
        }
    } else {
        for (int i = t; i < NB_BUCK; i += 256) cursor[i] = 0;
        if (t == 0) dinv[N_NODES] = 0.f;                  // sentinel weight
        if (t < 128) h[(size_t)N_NODES * 128 + t] = 0;    // sentinel h row
    }
}

// ---- k_fuse1: R8-exact (proven). Partition + GEMM1, 4 blocks/CU. ----
__global__ __launch_bounds__(256, 4) void k_fuse1(const int* __restrict__ ei,
                                                  int* __restrict__ cursor,
                                                  unsigned int* __restrict__ part,
                                                  const float* __restrict__ x,
                                                  const ushort* __restrict__ w1b,
                                                  ushort* __restrict__ h) {
    __shared__ __align__(16) ushort smem[128 * 136];   // 34816 B union
    int tid = threadIdx.x;

    if (blockIdx.x < NBLK_E) {
        // ---------- partition role (R1-exact) ----------
        int* lh    = (int*)smem;             // local hist, then local cursor (1563)
        int* lbase = lh + NB_BUCK;           // global base of this block's run (1563)
        for (int i = tid; i < NB_BUCK; i += 256) lh[i] = 0;
        __syncthreads();
        int e0 = blockIdx.x * EPB;
        int srcv[EPB / 256], dstv[EPB / 256];
        #pragma unroll
        for (int j = 0; j < EPB / 256; j++) {
            int e = e0 + j * 256 + tid;
            if (e < N_EDGES) {
                srcv[j] = ei[e];
                dstv[j] = ei[N_EDGES + e];
                atomicAdd(&lh[dstv[j] >> BUCK_SHIFT], 1);
            } else dstv[j] = -1;
        }
        __syncthreads();
        for (int i = tid; i < NB_BUCK; i += 256) {
            int c = lh[i];
            lbase[i] = (c > 0) ? (i * CAP + atomicAdd(&cursor[i], c)) : 0;
            lh[i] = 0;                        // becomes local cursor
        }
        __syncthreads();
        #pragma unroll
        for (int j = 0; j < EPB / 256; j++) {
            if (dstv[j] >= 0) {
                int bk = dstv[j] >> BUCK_SHIFT;
                int pos = lbase[bk] + atomicAdd(&lh[bk], 1);
                part[pos] = ((unsigned int)(dstv[j] & (BUCK_SZ - 1)) << 24) | (unsigned int)srcv[j];
            }
        }
        return;
    }

    // ---------- GEMM1 role: h = bf16(x @ W1), B direct from L2-hot w1b ----------
    typedef ushort (*tile_t)[136];
    tile_t As = (tile_t)smem;
    int row0 = (blockIdx.x - NBLK_E) * 128;
    const int M = N_NODES;

    #pragma unroll
    for (int i = 0; i < 16; i++) {
        int li = tid + i * 256;
        int r = li >> 5, c4 = li & 31;
        int grow = row0 + r; if (grow > M - 1) grow = M - 1;
        float4 v = *(const float4*)(x + (size_t)grow * 128 + c4 * 4);
        ushort4 o;
        o.x = f2b(v.x); o.y = f2b(v.y); o.z = f2b(v.z); o.w = f2b(v.w);
        *(ushort4*)&As[r][c4 * 4] = o;
    }
    __syncthreads();

    int wave = tid >> 6, lane = tid & 63;
    int lr = lane & 15, lq = lane >> 4;
    int wm0 = (wave & 1) * 64;
    int wn0 = (wave >> 1) * 64;

    f4_t acc[4][4];
    #pragma unroll
    for (int mi = 0; mi < 4; mi++)
        #pragma unroll
        for (int ni = 0; ni < 4; ni++) acc[mi][ni] = (f4_t){0.f, 0.f, 0.f, 0.f};

    #pragma unroll
    for (int kb = 0; kb < 4; kb++) {
        bf8_t af[4], bfr[4];
        #pragma unroll
        for (int mi = 0; mi < 4; mi++)
            af[mi] = *(const bf8_t*)&As[wm0 + mi * 16 + lr][kb * 32 + lq * 8];
        #pragma unroll
        for (int ni = 0; ni < 4; ni++)
            bfr[ni] = *(const bf8_t*)(w1b + (size_t)(wn0 + ni * 16 + lr) * 128 + kb * 32 + lq * 8);
        #pragma unroll
        for (int mi = 0; mi < 4; mi++)
            #pragma unroll
            for (int ni = 0; ni < 4; ni++)
                acc[mi][ni] = __builtin_amdgcn_mfma_f32_16x16x32_bf16(
                    af[mi], bfr[ni], acc[mi][ni], 0, 0, 0);
    }

    #pragma unroll
    for (int mi = 0; mi < 4; mi++) {
        #pragma unroll
        for (int r = 0; r < 4; r++) {
            int row = row0 + wm0 + mi * 16 + lq * 4 + r;
            if (row < M) {
                #pragma unroll
                for (int ni = 0; ni < 4; ni++)
                    h[(size_t)row * 128 + wn0 + ni * 16 + lr] = f2b(acc[mi][ni][r]);
            }
        }
    }
}

// ---- k_deg: per-bucket degree hist -> dinv. Tiny (6.4MB read), high occupancy.
// Must complete before k_agg3 (remote-src dinv reads). ----
__global__ __launch_bounds__(256) void k_deg(const unsigned int* __restrict__ part,
                                             const int* __restrict__ cursor,
                                             float* __restrict__ dinv) {
    __shared__ int ldeg[BUCK_SZ];
    int t = threadIdx.x, b = blockIdx.x;
    int cnt = cursor[b];
    int node0 = b << BUCK_SHIFT;
    if (t < BUCK_SZ) ldeg[t] = 0;
    __syncthreads();
    for (int i = t; i < cnt; i += 256)
        atomicAdd(&ldeg[part[(size_t)b * CAP + i] >> 24], 1);
    __syncthreads();
    if (t < BUCK_SZ && node0 + t < N_NODES)
        dinv[node0 + t] = rsqrtf((float)(ldeg[t] + 1));   // +1: self-loop
}

// ---- k_agg3: fused CSR-build (in LDS) + aggregation + GEMM2. Block = one
// 64-node bucket, 4 waves x 16 nodes. The csr front (hist/scan/scatter) runs
// as per-block prologue whose latency overlaps other blocks' gathers
// (6 blocks/CU); ssrc/offs/pcnt global traffic deleted. Gather inner loop is
// agg2's proven body with the index stream read from LDS. ----
__global__ __launch_bounds__(256, 6) void k_agg3(const ushort* __restrict__ h,
                                                 const unsigned int* __restrict__ part,
                                                 const int* __restrict__ cursor,
                                                 const float* __restrict__ dinv,
                                                 const float* __restrict__ b1,
                                                 const ushort* __restrict__ w2b,
                                                 const float* __restrict__ b2,
                                                 float* __restrict__ out) {
    __shared__ int ldeg[BUCK_SZ], lsc[BUCK_SZ], lcur[BUCK_SZ], sob[BUCK_SZ];
    __shared__ int sorted[PCAP];               // 7936 B, bucket CSR (LDS-only)
    __shared__ ushort As[BUCK_SZ][136];        // 17408 B, aggregated h2 rows
    int t = threadIdx.x, b = blockIdx.x;
    size_t rbeg = (size_t)b * CAP;
    int cnt = cursor[b];
    int node0 = b << BUCK_SHIFT;

    if (t < BUCK_SZ) ldeg[t] = 0;
    for (int i = t; i < PCAP; i += 256) sorted[i] = N_NODES;   // sentinel pre-fill
    __syncthreads();
    for (int i = t; i < cnt; i += 256)
        atomicAdd(&ldeg[part[rbeg + i] >> 24], 1);             // pass 1: hist
    __syncthreads();
    int v = 0, pv = 0;
    if (t < BUCK_SZ) {
        v = ldeg[t];
        pv = (v + 7) & ~7;
        lsc[t] = pv;
    }
    __syncthreads();
    for (int off = 1; off < BUCK_SZ; off <<= 1) {              // scan padded degs
        int add = 0;
        if (t < BUCK_SZ && t >= off) add = lsc[t - off];
        __syncthreads();
        if (t < BUCK_SZ) lsc[t] += add;
        __syncthreads();
    }
    if (t < BUCK_SZ) {
        sob[t] = lsc[t] - pv;                  // local padded offset
        lcur[t] = 0;
    }
    __syncthreads();
    for (int i = t; i < cnt; i += 256) {       // pass 2: scatter (part L2-hot)
        unsigned int u = part[rbeg + i];
        int d = u >> 24;
        int pos = atomicAdd(&lcur[d], 1);
        sorted[sob[d] + pos] = (int)(u & 0xFFFFFFu);
    }
    __syncthreads();

    // ---- gather phase: wave w aggregates nodes w*16 .. w*16+15 ----
    int wave = t >> 6, lane = t & 63;
    const unsigned int* hp = (const unsigned int*)h;
    float2 bb = ((const float2*)b1)[lane];

    #pragma unroll 1
    for (int j = 0; j < 16; j++) {
        int ln = wave * 16 + j;                // local node id (As row)
        int n = node0 + ln;
        if (n < N_NODES) {                     // wave-uniform guard
            int lsob = __builtin_amdgcn_readfirstlane(sob[ln]);
            int iters = (__builtin_amdgcn_readfirstlane(ldeg[ln]) + 7) >> 3;
            const int* sp = sorted + lsob;

            float ax0 = 0.f, ay0 = 0.f, ax1 = 0.f, ay1 = 0.f;
            float ax2 = 0.f, ay2 = 0.f, ax3 = 0.f, ay3 = 0.f;
            for (int it = 0; it < iters; it++) {
                int4 q0 = *(const int4*)(sp + it * 8);      // ds_read_b128
                int4 q1 = *(const int4*)(sp + it * 8 + 4);
                int s0 = __builtin_amdgcn_readfirstlane(q0.x);
                int s1 = __builtin_amdgcn_readfirstlane(q0.y);
                int s2 = __builtin_amdgcn_readfirstlane(q0.z);
                int s3 = __builtin_amdgcn_readfirstlane(q0.w);
                int s4 = __builtin_amdgcn_readfirstlane(q1.x);
                int s5 = __builtin_amdgcn_readfirstlane(q1.y);
                int s6 = __builtin_amdgcn_readfirstlane(q1.z);
                int s7 = __builtin_amdgcn_readfirstlane(q1.w);
                unsigned int u0 = (hp + ((unsigned)s0 << 6))[lane];
                unsigned int u1 = (hp + ((unsigned)s1 << 6))[lane];
                unsigned int u2 = (hp + ((unsigned)s2 << 6))[lane];
                unsigned int u3 = (hp + ((unsigned)s3 << 6))[lane];
                unsigned int u4 = (hp + ((unsigned)s4 << 6))[lane];
                unsigned int u5 = (hp + ((unsigned)s5 << 6))[lane];
                unsigned int u6 = (hp + ((unsigned)s6 << 6))[lane];
                unsigned int u7 = (hp + ((unsigned)s7 << 6))[lane];
                float w0 = dinv[s0], w1 = dinv[s1], w2 = dinv[s2], w3 = dinv[s3];
                float w4 = dinv[s4], w5 = dinv[s5], w6 = dinv[s6], w7 = dinv[s7];
                ax0 = fmaf(b2f_lo(u0), w0, ax0); ay0 = fmaf(b2f_hi(u0), w0, ay0);
                ax1 = fmaf(b2f_lo(u1), w1, ax1); ay1 = fmaf(b2f_hi(u1), w1, ay1);
                ax2 = fmaf(b2f_lo(u2), w2, ax2); ay2 = fmaf(b2f_hi(u2), w2, ay2);
                ax3 = fmaf(b2f_lo(u3), w3, ax3); ay3 = fmaf(b2f_hi(u3), w3, ay3);
                ax0 = fmaf(b2f_lo(u4), w4, ax0); ay0 = fmaf(b2f_hi(u4), w4, ay0);
                ax1 = fmaf(b2f_lo(u5), w5, ax1); ay1 = fmaf(b2f_hi(u5), w5, ay1);
                ax2 = fmaf(b2f_lo(u6), w6, ax2); ay2 = fmaf(b2f_hi(u6), w6, ay2);
                ax3 = fmaf(b2f_lo(u7), w7, ax3); ay3 = fmaf(b2f_hi(u7), w7, ay3);
            }
            unsigned int us = hp[(size_t)n * 64 + lane];     // self term
            float dn = rsqrtf((float)(__builtin_amdgcn_readfirstlane(ldeg[ln]) + 1));
            float rx = (ax0 + ax1 + ax2 + ax3 + b2f_lo(us) * dn) * dn + bb.x;
            float ry = (ay0 + ay1 + ay2 + ay3 + b2f_hi(us) * dn) * dn + bb.y;
            rx = rx > 0.f ? rx : 0.f;
            ry = ry > 0.f ? ry : 0.f;
            *(unsigned int*)&As[ln][lane * 2] =
                ((unsigned int)f2b(ry) << 16) | (unsigned int)f2b(rx);
        } else {
            *(unsigned int*)&As[ln][lane * 2] = 0;           // keep MFMA input clean
        }
    }
    __syncthreads();

    // ---- GEMM2: (64x128 As) @ W2 -> 64x64. Wave w -> cols [w*16, w*16+16). ----
    int lr = lane & 15, lq = lane >> 4;
    f4_t acc[4];
    #pragma unroll
    for (int mi = 0; mi < 4; mi++) acc[mi] = (f4_t){0.f, 0.f, 0.f, 0.f};
    #pragma unroll
    for (int kb = 0; kb < 4; kb++) {
        bf8_t bfv = *(const bf8_t*)(w2b + (size_t)(wave * 16 + lr) * 128 + kb * 32 + lq * 8);
        #pragma unroll
        for (int mi = 0; mi < 4; mi++) {
            bf8_t af = *(const bf8_t*)&As[mi * 16 + lr][kb * 32 + lq * 8];
            acc[mi] = __builtin_amdgcn_mfma_f32_16x16x32_bf16(af, bfv, acc[mi], 0, 0, 0);
        }
    }
    int col = wave * 16 + lr;
    float bv = b2[col];
    #pragma unroll
    for (int mi = 0; mi < 4; mi++) {
        #pragma unroll
        for (int r = 0; r < 4; r++) {
            int node = node0 + mi * 16 + lq * 4 + r;
            if (node < N_NODES)
                out[(size_t)node * 64 + col] = acc[mi][r] + bv;
        }
    }
}

// ---------------- launch ----------------

extern "C" void kernel_launch(void* const* d_in, const int* in_sizes, int n_in,
                              void* d_out, int out_size, void* d_ws, size_t ws_size,
                              hipStream_t stream) {
    const float* x  = (const float*)d_in[0];
    const float* W1 = (const float*)d_in[1];
    const float* b1 = (const float*)d_in[2];
    const float* W2 = (const float*)d_in[3];
    const float* b2 = (const float*)d_in[4];
    const int*   ei = (const int*)d_in[5];
    float* out = (float*)d_out;

    char* w = (char*)d_ws;
    size_t off = 0;
    auto alloc = [&](size_t bytes) -> void* {
        void* p = w + off;
        off += (bytes + 255) & ~(size_t)255;
        return p;
    };
    ushort* h      = (ushort*)alloc((size_t)(N_NODES + 1) * HIDDEN * 2);  // +1 sentinel row
    float* dinv    = (float*)alloc((size_t)(N_NODES + 1) * 4);
    unsigned int* part = (unsigned int*)alloc((size_t)NB_BUCK * CAP * 4);
    int*   cursor  = (int*)alloc((size_t)NB_BUCK * 4);
    ushort* w1b    = (ushort*)alloc((size_t)HIDDEN * IN_DIM * 2);
    ushort* w2b    = (ushort*)alloc((size_t)OUT_DIM * HIDDEN * 2);

    k_prep<<<13, 256, 0, stream>>>(W1, W2, w1b, w2b, cursor, dinv, h);
    k_fuse1<<<NBLK_E + GB1, 256, 0, stream>>>(ei, cursor, part, x, w1b, h);
    k_deg<<<NB_BUCK, 256, 0, stream>>>(part, cursor, dinv);
    k_agg3<<<NB_BUCK, 256, 0, stream>>>(h, part, cursor, dinv, b1, w2b, b2, out);
}